// Round 2
// 684.560 us; speedup vs baseline: 1.0076x; 1.0076x over previous
//
#include <hip/hip_runtime.h>
#include <math.h>

#define LRELU_SLOPE 0.2f

typedef float f32x4 __attribute__((ext_vector_type(4)));

__device__ __forceinline__ float lrelu(float x){ return x >= 0.f ? x : LRELU_SLOPE*x; }
__device__ __forceinline__ float eluf(float x){ return x > 0.f ? x : expm1f(x); }

// ---------------------------------------------------------------------------
// CSR build (by dst). Edge list = edge_index columns + n self loops.
// ---------------------------------------------------------------------------
__global__ void k_hist(const int* __restrict__ ei, int E, int n, int* __restrict__ cnt){
    int e = blockIdx.x*blockDim.x + threadIdx.x;
    int NE = E + n;
    if (e >= NE) return;
    int d = (e < E) ? ei[E + e] : (e - E);
    atomicAdd(&cnt[d], 1);
}

__global__ __launch_bounds__(1024) void k_scan(const int* __restrict__ cnt, int n,
                                               int* __restrict__ off, int* __restrict__ cur){
    __shared__ int part[1024];
    const int ITEMS = (n + 1023) / 1024;
    int t = threadIdx.x;
    int base = t * ITEMS;
    int s = 0;
    for (int i = 0; i < ITEMS; i++){ int idx = base + i; if (idx < n) s += cnt[idx]; }
    part[t] = s;
    __syncthreads();
    for (int d = 1; d < 1024; d <<= 1){
        int v = 0;
        if (t >= d) v = part[t - d];
        __syncthreads();
        if (t >= d) part[t] += v;
        __syncthreads();
    }
    int excl = part[t] - s;   // exclusive prefix of this thread's chunk
    for (int i = 0; i < ITEMS; i++){
        int idx = base + i;
        if (idx < n){ off[idx] = excl; cur[idx] = excl; excl += cnt[idx]; }
    }
    if (t == 1023) off[n] = part[1023];
}

__global__ void k_scatter(const int* __restrict__ ei, int E, int n,
                          int* __restrict__ cur, int* __restrict__ esrc){
    int e = blockIdx.x*blockDim.x + threadIdx.x;
    int NE = E + n;
    if (e >= NE) return;
    int s = (e < E) ? ei[e]     : (e - E);
    int d = (e < E) ? ei[E + e] : (e - E);
    int pos = atomicAdd(&cur[d], 1);
    esrc[pos] = s;
}

// ---------------------------------------------------------------------------
// fp32 GEMM: C[M,N] = A[M,K] @ B[N,K]^T (+bias). 64x64 tile, 256 threads,
// 4x4 microtile. K multiple of 32, N multiple of 64; M ragged (guarded).
// ---------------------------------------------------------------------------
__global__ __launch_bounds__(256) void k_gemm_nt(
    const float* __restrict__ A, const float* __restrict__ B,
    const float* __restrict__ bias, float* __restrict__ C,
    int M, int N, int K)
{
    const int BM = 64, BN = 64, BK = 32, PAD = 4;
    __shared__ float As[BK][BM + PAD];
    __shared__ float Bs[BK][BN + PAD];
    int tid = threadIdx.x;
    int tx = tid & 15;          // m direction (16)
    int ty = tid >> 4;          // n direction (16)
    int m0 = blockIdx.x * BM;
    int n0 = blockIdx.y * BN;
    float acc[4][4] = {};

    int lm = tid >> 3;          // 0..31
    int lk = (tid & 7) * 4;     // 0,4,...,28

    for (int k0 = 0; k0 < K; k0 += BK){
        #pragma unroll
        for (int r = 0; r < 2; r++){
            int m = lm + 32*r;
            int row = m0 + m;
            float4 v = make_float4(0.f,0.f,0.f,0.f);
            if (row < M) v = *(const float4*)&A[(size_t)row*K + k0 + lk];
            As[lk+0][m] = v.x; As[lk+1][m] = v.y; As[lk+2][m] = v.z; As[lk+3][m] = v.w;
        }
        #pragma unroll
        for (int r = 0; r < 2; r++){
            int nn = lm + 32*r;
            int col = n0 + nn;
            float4 v = make_float4(0.f,0.f,0.f,0.f);
            if (col < N) v = *(const float4*)&B[(size_t)col*K + k0 + lk];
            Bs[lk+0][nn] = v.x; Bs[lk+1][nn] = v.y; Bs[lk+2][nn] = v.z; Bs[lk+3][nn] = v.w;
        }
        __syncthreads();
        #pragma unroll
        for (int kk = 0; kk < BK; kk++){
            float4 a = *(const float4*)&As[kk][tx*4];
            float4 b = *(const float4*)&Bs[kk][ty*4];
            float av[4] = {a.x,a.y,a.z,a.w};
            float bv[4] = {b.x,b.y,b.z,b.w};
            #pragma unroll
            for (int i = 0; i < 4; i++)
                #pragma unroll
                for (int j = 0; j < 4; j++)
                    acc[i][j] = fmaf(av[i], bv[j], acc[i][j]);
        }
        __syncthreads();
    }

    float4 bb = make_float4(0.f,0.f,0.f,0.f);
    if (bias) bb = *(const float4*)&bias[n0 + ty*4];
    #pragma unroll
    for (int i = 0; i < 4; i++){
        int row = m0 + tx*4 + i;
        if (row >= M) continue;
        float4 v = make_float4(acc[i][0]+bb.x, acc[i][1]+bb.y, acc[i][2]+bb.z, acc[i][3]+bb.w);
        *(float4*)&C[(size_t)row*N + n0 + ty*4] = v;
    }
}

// ---------------------------------------------------------------------------
// Per-node attention scalars, vectorized. One wave per node.
// ---------------------------------------------------------------------------
__global__ __launch_bounds__(64) void k_att4(
    const float* __restrict__ h, const float* __restrict__ att_s,
    const float* __restrict__ att_d, int n,
    float* __restrict__ as_, float* __restrict__ ad_)
{
    int i = blockIdx.x, l = threadIdx.x;
    const float4* hr = (const float4*)(h + (size_t)i * 512);
    float4 v0 = hr[l*2], v1 = hr[l*2 + 1];
    int hh = l >> 4;
    const float4* sp = (const float4*)(att_s + hh*128 + (l & 15)*8);
    const float4* dp = (const float4*)(att_d + hh*128 + (l & 15)*8);
    float4 s0 = sp[0], s1v = sp[1];
    float4 d0 = dp[0], d1v = dp[1];
    float ps = v0.x*s0.x + v0.y*s0.y + v0.z*s0.z + v0.w*s0.w
             + v1.x*s1v.x + v1.y*s1v.y + v1.z*s1v.z + v1.w*s1v.w;
    float pd = v0.x*d0.x + v0.y*d0.y + v0.z*d0.z + v0.w*d0.w
             + v1.x*d1v.x + v1.y*d1v.y + v1.z*d1v.z + v1.w*d1v.w;
    #pragma unroll
    for (int o = 8; o > 0; o >>= 1){ ps += __shfl_xor(ps, o); pd += __shfl_xor(pd, o); }
    if ((l & 15) == 0){ as_[(size_t)i*4 + hh] = ps; ad_[(size_t)i*4 + hh] = pd; }
}

__global__ __launch_bounds__(64) void k_att1(
    const float* __restrict__ h, const float* __restrict__ att_s,
    const float* __restrict__ att_d, int n,
    float* __restrict__ as_, float* __restrict__ ad_)
{
    int i = blockIdx.x, l = threadIdx.x;
    float2 v  = ((const float2*)(h + (size_t)i * 128))[l];
    float2 s  = ((const float2*)att_s)[l];
    float2 dd = ((const float2*)att_d)[l];
    float ps = v.x*s.x + v.y*s.y;
    float pd = v.x*dd.x + v.y*dd.y;
    #pragma unroll
    for (int o = 32; o > 0; o >>= 1){ ps += __shfl_xor(ps, o); pd += __shfl_xor(pd, o); }
    if (l == 0){ as_[i] = ps; ad_[i] = pd; }
}

// ---------------------------------------------------------------------------
// GAT softmax + aggregation, H=4 (F=512). One block (4 waves) per dst node.
// Single pass (no segment-max; exp arg clamped at 80). Per 128-edge chunk:
// stage src + exp-weights, then wave w accumulates edges w, w+4, ... reading
// the 512-float source row as 2 x float4 per lane. Denominator fused;
// normalize in epilogue after 8 KB LDS cross-wave reduction.
// ---------------------------------------------------------------------------
__global__ __launch_bounds__(256) void k_agg4(
    const float* __restrict__ hfeat,   // n x 512
    const float* __restrict__ as_,     // n x 4
    const float* __restrict__ ad_,     // n x 4
    const int* __restrict__ off, const int* __restrict__ esrc,
    const float* __restrict__ bias,    // 512
    float* __restrict__ out, int n)
{
    const int CH = 128;
    int d = blockIdx.x, t = threadIdx.x;
    int lane = t & 63, wv = t >> 6;

    __shared__ int   src_l[CH];
    __shared__ float exw[CH][4];
    __shared__ float dsum[4];
    __shared__ __align__(16) float part[4][512];

    int e0 = off[d], e1 = off[d+1];

    float ad0 = ad_[(size_t)d*4+0], ad1 = ad_[(size_t)d*4+1],
          ad2 = ad_[(size_t)d*4+2], ad3 = ad_[(size_t)d*4+3];

    float acc[8];
    #pragma unroll
    for (int j = 0; j < 8; j++) acc[j] = 0.f;
    float dtot = 0.f;

    for (int cb = e0; cb < e1; cb += CH){
        int ce = min(CH, e1 - cb);
        for (int e = t; e < ce; e += 256){
            int s = esrc[cb + e];
            src_l[e] = s;
            float4 a4 = ((const float4*)as_)[s];
            exw[e][0] = expf(fminf(lrelu(a4.x + ad0), 80.f));
            exw[e][1] = expf(fminf(lrelu(a4.y + ad1), 80.f));
            exw[e][2] = expf(fminf(lrelu(a4.z + ad2), 80.f));
            exw[e][3] = expf(fminf(lrelu(a4.w + ad3), 80.f));
        }
        __syncthreads();
        // denominator partial: wave wv owns head wv
        {
            float v = 0.f;
            for (int e = lane; e < ce; e += 64) v += exw[e][wv];
            #pragma unroll
            for (int o = 32; o > 0; o >>= 1) v += __shfl_xor(v, o);
            dtot += v;
        }
        // features: wave wv takes edges wv, wv+4, ...
        for (int e = wv; e < ce; e += 4){
            int s = src_l[e];
            float w = exw[e][lane >> 4];
            const float4* hp = (const float4*)(hfeat + (size_t)s*512 + lane*8);
            float4 u0 = hp[0], u1 = hp[1];
            acc[0] = fmaf(w, u0.x, acc[0]);
            acc[1] = fmaf(w, u0.y, acc[1]);
            acc[2] = fmaf(w, u0.z, acc[2]);
            acc[3] = fmaf(w, u0.w, acc[3]);
            acc[4] = fmaf(w, u1.x, acc[4]);
            acc[5] = fmaf(w, u1.y, acc[5]);
            acc[6] = fmaf(w, u1.z, acc[6]);
            acc[7] = fmaf(w, u1.w, acc[7]);
        }
        __syncthreads();
    }

    if (lane == 0) dsum[wv] = dtot;
    float4* pr = (float4*)&part[wv][lane*8];
    pr[0] = make_float4(acc[0], acc[1], acc[2], acc[3]);
    pr[1] = make_float4(acc[4], acc[5], acc[6], acc[7]);
    __syncthreads();

    #pragma unroll
    for (int r = 0; r < 2; r++){
        int c = t + r*256;
        float sgm = part[0][c] + part[1][c] + part[2][c] + part[3][c];
        float val = sgm / (dsum[c >> 7] + 1e-16f) + bias[c];
        out[(size_t)d*512 + c] = eluf(val);
    }
}

// ---------------------------------------------------------------------------
// Same, H=1 (F=128). Half-wave per edge; 8 parallel edge streams per block.
// ---------------------------------------------------------------------------
__global__ __launch_bounds__(256) void k_agg1(
    const float* __restrict__ hfeat,   // n x 128
    const float* __restrict__ as_,     // n
    const float* __restrict__ ad_,     // n
    const int* __restrict__ off, const int* __restrict__ esrc,
    const float* __restrict__ bias,    // 128
    float* __restrict__ out, int n)
{
    const int CH = 128;
    int d = blockIdx.x, t = threadIdx.x;
    int lane = t & 63, wv = t >> 6;
    int half = lane >> 5, l5 = lane & 31;

    __shared__ int   src_l[CH];
    __shared__ float exw1[CH];
    __shared__ float dsum1;
    __shared__ __align__(16) float part[8][128];

    int e0 = off[d], e1 = off[d+1];
    float adl = ad_[d];

    float4 acc = make_float4(0.f, 0.f, 0.f, 0.f);
    float dtot = 0.f;

    for (int cb = e0; cb < e1; cb += CH){
        int ce = min(CH, e1 - cb);
        for (int e = t; e < ce; e += 256){
            int s = esrc[cb + e];
            src_l[e] = s;
            exw1[e] = expf(fminf(lrelu(as_[s] + adl), 80.f));
        }
        __syncthreads();
        if (wv == 0){
            float v = 0.f;
            for (int e = lane; e < ce; e += 64) v += exw1[e];
            #pragma unroll
            for (int o = 32; o > 0; o >>= 1) v += __shfl_xor(v, o);
            dtot += v;
        }
        int p = wv*2 + half;
        for (int e = p; e < ce; e += 8){
            int s = src_l[e];
            float w = exw1[e];
            float4 u = *(const float4*)(hfeat + (size_t)s*128 + l5*4);
            acc.x = fmaf(w, u.x, acc.x);
            acc.y = fmaf(w, u.y, acc.y);
            acc.z = fmaf(w, u.z, acc.z);
            acc.w = fmaf(w, u.w, acc.w);
        }
        __syncthreads();
    }

    if (t == 0) dsum1 = dtot;
    ((float4*)&part[wv*2 + half][0])[l5] = acc;
    __syncthreads();

    if (t < 128){
        float sgm = 0.f;
        #pragma unroll
        for (int p = 0; p < 8; p++) sgm += part[p][t];
        float val = sgm / (dsum1 + 1e-16f) + bias[t];
        out[(size_t)d*128 + t] = eluf(val);
    }
}

// ---------------------------------------------------------------------------
// Edge scores: s1[i] = h3[i,:]·w1 + bedge, s2[i] = h3[i,:]·w2. One wave/node.
// ---------------------------------------------------------------------------
__global__ __launch_bounds__(64) void k_score(
    const float* __restrict__ h3, const float* __restrict__ wedge,
    const float* __restrict__ bedge, int n,
    float* __restrict__ s1, float* __restrict__ s2)
{
    int i = blockIdx.x, l = threadIdx.x;
    float2 v  = ((const float2*)(h3 + (size_t)i * 128))[l];
    float2 w1 = ((const float2*)wedge)[l];
    float2 w2 = ((const float2*)(wedge + 128))[l];
    float p1 = v.x*w1.x + v.y*w1.y;
    float p2 = v.x*w2.x + v.y*w2.y;
    #pragma unroll
    for (int o = 32; o > 0; o >>= 1){ p1 += __shfl_xor(p1, o); p2 += __shfl_xor(p2, o); }
    if (l == 0){ s1[i] = p1 + bedge[0]; s2[i] = p2; }
}

// ---------------------------------------------------------------------------
// out[i,j] = s1[i] + s2[j]. One block per row, nontemporal ext-vector stores.
// ---------------------------------------------------------------------------
__global__ __launch_bounds__(256) void k_outer(
    const float* __restrict__ s1, const float* __restrict__ s2,
    float* __restrict__ out, int n)
{
    int i = blockIdx.x;
    float a = s1[i];
    f32x4* orow = (f32x4*)(out + (size_t)i * n);
    const f32x4* s2v = (const f32x4*)s2;
    int nq = n >> 2;
    for (int j = threadIdx.x; j < nq; j += blockDim.x){
        f32x4 b = s2v[j];
        f32x4 r = b + a;
        __builtin_nontemporal_store(r, &orow[j]);
    }
    // ragged tail (n % 4) — not hit for n=10000 but kept for safety
    int rem0 = nq << 2;
    for (int j = rem0 + threadIdx.x; j < n; j += blockDim.x)
        out[(size_t)i * n + j] = a + s2[j];
}

// ---------------------------------------------------------------------------
extern "C" void kernel_launch(void* const* d_in, const int* in_sizes, int n_in,
                              void* d_out, int out_size, void* d_ws, size_t ws_size,
                              hipStream_t stream) {
    const float* x     = (const float*)d_in[0];
    const int*   ei    = (const int*)  d_in[1];
    const float* W0    = (const float*)d_in[2];
    const float* as0w  = (const float*)d_in[3];
    const float* ad0w  = (const float*)d_in[4];
    const float* b0    = (const float*)d_in[5];
    const float* W1    = (const float*)d_in[6];
    const float* as1w  = (const float*)d_in[7];
    const float* ad1w  = (const float*)d_in[8];
    const float* b1    = (const float*)d_in[9];
    const float* Wout  = (const float*)d_in[10];
    const float* boutp = (const float*)d_in[11];
    const float* Wedge = (const float*)d_in[12];
    const float* bedge = (const float*)d_in[13];

    const int hid    = in_sizes[7];                 // 128
    const int heads  = in_sizes[3] / hid;           // 4
    const int in_dim = in_sizes[2] / (heads * hid); // 128
    const int n      = in_sizes[0] / in_dim;        // 10000
    const int E      = in_sizes[1] / 2;             // 320000
    const int NE     = E + n;
    const int F0     = heads * hid;                 // 512

    // ---- workspace carving ----
    char* ws = (char*)d_ws;
    size_t pos = 0;
    auto alloc = [&](size_t bytes) -> void* {
        pos = (pos + 255) & ~size_t(255);
        void* p = ws + pos;
        pos += bytes;
        return p;
    };
    float* a0s = (float*)alloc((size_t)n * heads * 4);
    float* a0d = (float*)alloc((size_t)n * heads * 4);
    float* a1s = (float*)alloc((size_t)n * 4);
    float* a1d = (float*)alloc((size_t)n * 4);
    float* s1  = (float*)alloc((size_t)n * 4);
    float* s2  = (float*)alloc((size_t)n * 4);
    int*   cnt = (int*)  alloc((size_t)n * 4);
    int*   offs= (int*)  alloc((size_t)(n + 1) * 4);
    int*   cur = (int*)  alloc((size_t)n * 4);

    // big buffers: in ws if they fit, else carve from d_out (dead before k_outer)
    auto al = [](size_t b){ return (b + 255) & ~size_t(255); };
    size_t b_esrc = al((size_t)NE * 4);
    size_t b_h0   = al((size_t)n * F0 * 4);
    size_t b_o1   = al((size_t)n * F0 * 4);
    size_t b_h1   = al((size_t)n * hid * 4);
    size_t b_o2   = al((size_t)n * hid * 4);
    size_t b_h3   = al((size_t)n * hid * 4);
    size_t big_need = b_esrc + b_h0 + b_o1 + b_h1 + b_o2 + b_h3;
    size_t small_end = (pos + 255) & ~size_t(255);
    char* big = (small_end + big_need <= ws_size) ? (ws + small_end) : (char*)d_out;
    size_t bp = 0;
    int*   esrc = (int*)  (big + bp); bp += b_esrc;
    float* h0   = (float*)(big + bp); bp += b_h0;
    float* o1   = (float*)(big + bp); bp += b_o1;
    float* h1   = (float*)(big + bp); bp += b_h1;
    float* o2   = (float*)(big + bp); bp += b_o2;
    float* h3   = (float*)(big + bp); bp += b_h3;

    // ---- CSR build (shared by both GAT layers) ----
    (void)hipMemsetAsync(cnt, 0, (size_t)n * 4, stream);
    int tb = 256, gbE = (NE + tb - 1) / tb;
    k_hist   <<<gbE, tb, 0, stream>>>(ei, E, n, cnt);
    k_scan   <<<1, 1024, 0, stream>>>(cnt, n, offs, cur);
    k_scatter<<<gbE, tb, 0, stream>>>(ei, E, n, cur, esrc);

    int gx = (n + 63) / 64;

    // ---- Layer 1: h0 = x @ W0^T ; attention scalars ; aggregate -> o1 ----
    k_gemm_nt<<<dim3(gx, F0/64), 256, 0, stream>>>(x, W0, nullptr, h0, n, F0, in_dim);
    k_att4   <<<n, 64, 0, stream>>>(h0, as0w, ad0w, n, a0s, a0d);
    k_agg4   <<<n, 256, 0, stream>>>(h0, a0s, a0d, offs, esrc, b0, o1, n);

    // ---- Layer 2: h1 = o1 @ W1^T ; aggregate -> o2 ----
    k_gemm_nt<<<dim3(gx, hid/64), 256, 0, stream>>>(o1, W1, nullptr, h1, n, hid, F0);
    k_att1   <<<n, 64, 0, stream>>>(h1, as1w, ad1w, n, a1s, a1d);
    k_agg1   <<<n, 256, 0, stream>>>(h1, a1s, a1d, offs, esrc, b1, o2, n);

    // ---- h3 = o2 @ Wout^T + bout ----
    k_gemm_nt<<<dim3(gx, hid/64), 256, 0, stream>>>(o2, Wout, boutp, h3, n, hid, hid);

    // ---- edge scores + outer sum ----
    k_score<<<n, 64, 0, stream>>>(h3, Wedge, bedge, n, s1, s2);
    k_outer<<<n, 256, 0, stream>>>(s1, s2, (float*)d_out, n);
}

// Round 3
// 650.338 us; speedup vs baseline: 1.0606x; 1.0526x over previous
//
#include <hip/hip_runtime.h>
#include <math.h>

#define LRELU_SLOPE 0.2f

typedef float f32x4 __attribute__((ext_vector_type(4)));
typedef _Float16 h16;
typedef h16 h16x8 __attribute__((ext_vector_type(8)));
typedef h16 h16x4 __attribute__((ext_vector_type(4)));

__device__ __forceinline__ float lrelu(float x){ return x >= 0.f ? x : LRELU_SLOPE*x; }
__device__ __forceinline__ float eluf(float x){ return x > 0.f ? x : expm1f(x); }

// ---------------------------------------------------------------------------
// CSR build (by dst). Edge list = edge_index columns + n self loops.
// ---------------------------------------------------------------------------
__global__ void k_hist(const int* __restrict__ ei, int E, int n, int* __restrict__ cnt){
    int e = blockIdx.x*blockDim.x + threadIdx.x;
    int NE = E + n;
    if (e >= NE) return;
    int d = (e < E) ? ei[E + e] : (e - E);
    atomicAdd(&cnt[d], 1);
}

__global__ __launch_bounds__(1024) void k_scan(const int* __restrict__ cnt, int n,
                                               int* __restrict__ off, int* __restrict__ cur){
    __shared__ int part[1024];
    const int ITEMS = (n + 1023) / 1024;
    int t = threadIdx.x;
    int base = t * ITEMS;
    int s = 0;
    for (int i = 0; i < ITEMS; i++){ int idx = base + i; if (idx < n) s += cnt[idx]; }
    part[t] = s;
    __syncthreads();
    for (int d = 1; d < 1024; d <<= 1){
        int v = 0;
        if (t >= d) v = part[t - d];
        __syncthreads();
        if (t >= d) part[t] += v;
        __syncthreads();
    }
    int excl = part[t] - s;   // exclusive prefix of this thread's chunk
    for (int i = 0; i < ITEMS; i++){
        int idx = base + i;
        if (idx < n){ off[idx] = excl; cur[idx] = excl; excl += cnt[idx]; }
    }
    if (t == 1023) off[n] = part[1023];
}

__global__ void k_scatter(const int* __restrict__ ei, int E, int n,
                          int* __restrict__ cur, int* __restrict__ esrc){
    int e = blockIdx.x*blockDim.x + threadIdx.x;
    int NE = E + n;
    if (e >= NE) return;
    int s = (e < E) ? ei[e]     : (e - E);
    int d = (e < E) ? ei[E + e] : (e - E);
    int pos = atomicAdd(&cur[d], 1);
    esrc[pos] = s;
}

// ---------------------------------------------------------------------------
// Fused fp32 GEMM + attention-dot epilogue, fp16 output.
// C[M,N] = A[M,K] @ B[N,K]^T  (no bias; GAT adds bias after aggregation).
// Epilogue: per-row partial dots vs att_s/att_d (head = col>>7), LDS-reduced,
// one global atomicAdd per row per block. as_/ad_ must be zero-initialized.
// 64x64 tile, 256 threads, 4x4 microtile. K mult of 32, N mult of 64 (and
// each 64-col block lies within one 128-wide head). M ragged (guarded).
// ---------------------------------------------------------------------------
template<int H>
__global__ __launch_bounds__(256) void k_gemm_h16_att(
    const float* __restrict__ A, const float* __restrict__ B,
    h16* __restrict__ C,
    const float* __restrict__ att_s, const float* __restrict__ att_d,
    float* __restrict__ as_, float* __restrict__ ad_,
    int M, int N, int K)
{
    const int BM = 64, BN = 64, BK = 32, PAD = 4;
    __shared__ float As[BK][BM + PAD];
    __shared__ float Bs[BK][BN + PAD];
    __shared__ float asl[64], adl[64];
    int tid = threadIdx.x;
    int tx = tid & 15;          // m direction (16)
    int ty = tid >> 4;          // n direction (16)
    int m0 = blockIdx.x * BM;
    int n0 = blockIdx.y * BN;
    float acc[4][4] = {};

    int lm = tid >> 3;          // 0..31
    int lk = (tid & 7) * 4;     // 0,4,...,28

    if (tid < 64){ asl[tid] = 0.f; adl[tid] = 0.f; }

    for (int k0 = 0; k0 < K; k0 += BK){
        #pragma unroll
        for (int r = 0; r < 2; r++){
            int m = lm + 32*r;
            int row = m0 + m;
            float4 v = make_float4(0.f,0.f,0.f,0.f);
            if (row < M) v = *(const float4*)&A[(size_t)row*K + k0 + lk];
            As[lk+0][m] = v.x; As[lk+1][m] = v.y; As[lk+2][m] = v.z; As[lk+3][m] = v.w;
        }
        #pragma unroll
        for (int r = 0; r < 2; r++){
            int nn = lm + 32*r;
            int col = n0 + nn;
            float4 v = make_float4(0.f,0.f,0.f,0.f);
            if (col < N) v = *(const float4*)&B[(size_t)col*K + k0 + lk];
            Bs[lk+0][nn] = v.x; Bs[lk+1][nn] = v.y; Bs[lk+2][nn] = v.z; Bs[lk+3][nn] = v.w;
        }
        __syncthreads();
        #pragma unroll
        for (int kk = 0; kk < BK; kk++){
            float4 a = *(const float4*)&As[kk][tx*4];
            float4 b = *(const float4*)&Bs[kk][ty*4];
            float av[4] = {a.x,a.y,a.z,a.w};
            float bv[4] = {b.x,b.y,b.z,b.w};
            #pragma unroll
            for (int i = 0; i < 4; i++)
                #pragma unroll
                for (int j = 0; j < 4; j++)
                    acc[i][j] = fmaf(av[i], bv[j], acc[i][j]);
        }
        __syncthreads();
    }

    // fp16 C write
    #pragma unroll
    for (int i = 0; i < 4; i++){
        int row = m0 + tx*4 + i;
        if (row >= M) continue;
        h16x4 hv;
        hv[0] = (h16)acc[i][0]; hv[1] = (h16)acc[i][1];
        hv[2] = (h16)acc[i][2]; hv[3] = (h16)acc[i][3];
        *(h16x4*)&C[(size_t)row*N + n0 + ty*4] = hv;
    }

    // attention-dot epilogue (fp32 accumulators, full precision)
    int head = (H == 1) ? 0 : (n0 >> 7);
    int cb = head*128 + (n0 & 127) + ty*4;
    float ws0 = att_s[cb+0], ws1 = att_s[cb+1], ws2 = att_s[cb+2], ws3 = att_s[cb+3];
    float wd0 = att_d[cb+0], wd1 = att_d[cb+1], wd2 = att_d[cb+2], wd3 = att_d[cb+3];
    #pragma unroll
    for (int i = 0; i < 4; i++){
        float ps = acc[i][0]*ws0 + acc[i][1]*ws1 + acc[i][2]*ws2 + acc[i][3]*ws3;
        float pd = acc[i][0]*wd0 + acc[i][1]*wd1 + acc[i][2]*wd2 + acc[i][3]*wd3;
        atomicAdd(&asl[tx*4+i], ps);
        atomicAdd(&adl[tx*4+i], pd);
    }
    __syncthreads();
    if (tid < 64){
        int row = m0 + tid;
        if (row < M){
            atomicAdd(&as_[(size_t)row*H + head], asl[tid]);
            atomicAdd(&ad_[(size_t)row*H + head], adl[tid]);
        }
    }
}

// ---------------------------------------------------------------------------
// Fused fp32 GEMM + bias + edge-score epilogue. No C write (h3 is dead
// otherwise): s1[i] += (h3[i,:blk])·w1, s2[i] += (h3[i,:blk])·w2 via atomics.
// s1/s2 must be zero-initialized. bedge added later in k_outer.
// ---------------------------------------------------------------------------
__global__ __launch_bounds__(256) void k_gemm_score(
    const float* __restrict__ A, const float* __restrict__ B,
    const float* __restrict__ bias,
    const float* __restrict__ w1, const float* __restrict__ w2,
    float* __restrict__ s1, float* __restrict__ s2,
    int M, int N, int K)
{
    const int BM = 64, BN = 64, BK = 32, PAD = 4;
    __shared__ float As[BK][BM + PAD];
    __shared__ float Bs[BK][BN + PAD];
    __shared__ float r1[64], r2[64];
    int tid = threadIdx.x;
    int tx = tid & 15;
    int ty = tid >> 4;
    int m0 = blockIdx.x * BM;
    int n0 = blockIdx.y * BN;
    float acc[4][4] = {};

    int lm = tid >> 3;
    int lk = (tid & 7) * 4;

    if (tid < 64){ r1[tid] = 0.f; r2[tid] = 0.f; }

    for (int k0 = 0; k0 < K; k0 += BK){
        #pragma unroll
        for (int r = 0; r < 2; r++){
            int m = lm + 32*r;
            int row = m0 + m;
            float4 v = make_float4(0.f,0.f,0.f,0.f);
            if (row < M) v = *(const float4*)&A[(size_t)row*K + k0 + lk];
            As[lk+0][m] = v.x; As[lk+1][m] = v.y; As[lk+2][m] = v.z; As[lk+3][m] = v.w;
        }
        #pragma unroll
        for (int r = 0; r < 2; r++){
            int nn = lm + 32*r;
            int col = n0 + nn;
            float4 v = make_float4(0.f,0.f,0.f,0.f);
            if (col < N) v = *(const float4*)&B[(size_t)col*K + k0 + lk];
            Bs[lk+0][nn] = v.x; Bs[lk+1][nn] = v.y; Bs[lk+2][nn] = v.z; Bs[lk+3][nn] = v.w;
        }
        __syncthreads();
        #pragma unroll
        for (int kk = 0; kk < BK; kk++){
            float4 a = *(const float4*)&As[kk][tx*4];
            float4 b = *(const float4*)&Bs[kk][ty*4];
            float av[4] = {a.x,a.y,a.z,a.w};
            float bv[4] = {b.x,b.y,b.z,b.w};
            #pragma unroll
            for (int i = 0; i < 4; i++)
                #pragma unroll
                for (int j = 0; j < 4; j++)
                    acc[i][j] = fmaf(av[i], bv[j], acc[i][j]);
        }
        __syncthreads();
    }

    int c0 = n0 + ty*4;
    float b0v = bias[c0+0], b1v = bias[c0+1], b2v = bias[c0+2], b3v = bias[c0+3];
    float wa0 = w1[c0+0], wa1 = w1[c0+1], wa2 = w1[c0+2], wa3 = w1[c0+3];
    float wb0 = w2[c0+0], wb1 = w2[c0+1], wb2 = w2[c0+2], wb3 = w2[c0+3];
    #pragma unroll
    for (int i = 0; i < 4; i++){
        float v0 = acc[i][0]+b0v, v1 = acc[i][1]+b1v, v2 = acc[i][2]+b2v, v3 = acc[i][3]+b3v;
        float p1 = v0*wa0 + v1*wa1 + v2*wa2 + v3*wa3;
        float p2 = v0*wb0 + v1*wb1 + v2*wb2 + v3*wb3;
        atomicAdd(&r1[tx*4+i], p1);
        atomicAdd(&r2[tx*4+i], p2);
    }
    __syncthreads();
    if (tid < 64){
        int row = m0 + tid;
        if (row < M){
            atomicAdd(&s1[row], r1[tid]);
            atomicAdd(&s2[row], r2[tid]);
        }
    }
}

// ---------------------------------------------------------------------------
// GAT softmax + aggregation, H=4 (F=512), fp16 features. One block (4 waves)
// per dst node. Single pass (no segment-max; exp arg clamped at 80).
// Per 128-edge chunk: stage src + exp-weights (fp32), then wave w accumulates
// edges w, w+4, ... reading the 512-half source row as 1 x 16B load per lane.
// Denominator fused; normalize in epilogue after 8 KB LDS cross-wave reduce.
// ---------------------------------------------------------------------------
__global__ __launch_bounds__(256) void k_agg4(
    const h16* __restrict__ hfeat,     // n x 512 (fp16)
    const float* __restrict__ as_,     // n x 4
    const float* __restrict__ ad_,     // n x 4
    const int* __restrict__ off, const int* __restrict__ esrc,
    const float* __restrict__ bias,    // 512
    float* __restrict__ out, int n)
{
    const int CH = 128;
    int d = blockIdx.x, t = threadIdx.x;
    int lane = t & 63, wv = t >> 6;

    __shared__ int   src_l[CH];
    __shared__ float exw[CH][4];
    __shared__ float dsum[4];
    __shared__ __align__(16) float part[4][512];

    int e0 = off[d], e1 = off[d+1];

    float ad0 = ad_[(size_t)d*4+0], ad1 = ad_[(size_t)d*4+1],
          ad2 = ad_[(size_t)d*4+2], ad3 = ad_[(size_t)d*4+3];

    float acc[8];
    #pragma unroll
    for (int j = 0; j < 8; j++) acc[j] = 0.f;
    float dtot = 0.f;

    for (int cb = e0; cb < e1; cb += CH){
        int ce = min(CH, e1 - cb);
        for (int e = t; e < ce; e += 256){
            int s = esrc[cb + e];
            src_l[e] = s;
            float4 a4 = ((const float4*)as_)[s];
            exw[e][0] = expf(fminf(lrelu(a4.x + ad0), 80.f));
            exw[e][1] = expf(fminf(lrelu(a4.y + ad1), 80.f));
            exw[e][2] = expf(fminf(lrelu(a4.z + ad2), 80.f));
            exw[e][3] = expf(fminf(lrelu(a4.w + ad3), 80.f));
        }
        __syncthreads();
        // denominator partial: wave wv owns head wv
        {
            float v = 0.f;
            for (int e = lane; e < ce; e += 64) v += exw[e][wv];
            #pragma unroll
            for (int o = 32; o > 0; o >>= 1) v += __shfl_xor(v, o);
            dtot += v;
        }
        // features: wave wv takes edges wv, wv+4, ...
        for (int e = wv; e < ce; e += 4){
            int s = src_l[e];
            float w = exw[e][lane >> 4];
            h16x8 u = ((const h16x8*)(hfeat + (size_t)s*512))[lane];
            acc[0] = fmaf(w, (float)u[0], acc[0]);
            acc[1] = fmaf(w, (float)u[1], acc[1]);
            acc[2] = fmaf(w, (float)u[2], acc[2]);
            acc[3] = fmaf(w, (float)u[3], acc[3]);
            acc[4] = fmaf(w, (float)u[4], acc[4]);
            acc[5] = fmaf(w, (float)u[5], acc[5]);
            acc[6] = fmaf(w, (float)u[6], acc[6]);
            acc[7] = fmaf(w, (float)u[7], acc[7]);
        }
        __syncthreads();
    }

    if (lane == 0) dsum[wv] = dtot;
    float4* pr = (float4*)&part[wv][lane*8];
    pr[0] = make_float4(acc[0], acc[1], acc[2], acc[3]);
    pr[1] = make_float4(acc[4], acc[5], acc[6], acc[7]);
    __syncthreads();

    #pragma unroll
    for (int r = 0; r < 2; r++){
        int c = t + r*256;
        float sgm = part[0][c] + part[1][c] + part[2][c] + part[3][c];
        float val = sgm / (dsum[c >> 7] + 1e-16f) + bias[c];
        out[(size_t)d*512 + c] = eluf(val);
    }
}

// ---------------------------------------------------------------------------
// Same, H=1 (F=128), fp16 features. Half-wave per edge (8B load per lane);
// 8 parallel edge streams per block, 8-way LDS partial reduction.
// ---------------------------------------------------------------------------
__global__ __launch_bounds__(256) void k_agg1(
    const h16* __restrict__ hfeat,     // n x 128 (fp16)
    const float* __restrict__ as_,     // n
    const float* __restrict__ ad_,     // n
    const int* __restrict__ off, const int* __restrict__ esrc,
    const float* __restrict__ bias,    // 128
    float* __restrict__ out, int n)
{
    const int CH = 128;
    int d = blockIdx.x, t = threadIdx.x;
    int lane = t & 63, wv = t >> 6;
    int half = lane >> 5, l5 = lane & 31;

    __shared__ int   src_l[CH];
    __shared__ float exw1[CH];
    __shared__ float dsum1;
    __shared__ __align__(16) float part[8][128];

    int e0 = off[d], e1 = off[d+1];
    float adl = ad_[d];

    float4 acc = make_float4(0.f, 0.f, 0.f, 0.f);
    float dtot = 0.f;

    for (int cb = e0; cb < e1; cb += CH){
        int ce = min(CH, e1 - cb);
        for (int e = t; e < ce; e += 256){
            int s = esrc[cb + e];
            src_l[e] = s;
            exw1[e] = expf(fminf(lrelu(as_[s] + adl), 80.f));
        }
        __syncthreads();
        if (wv == 0){
            float v = 0.f;
            for (int e = lane; e < ce; e += 64) v += exw1[e];
            #pragma unroll
            for (int o = 32; o > 0; o >>= 1) v += __shfl_xor(v, o);
            dtot += v;
        }
        int p = wv*2 + half;
        for (int e = p; e < ce; e += 8){
            int s = src_l[e];
            float w = exw1[e];
            h16x4 u = ((const h16x4*)(hfeat + (size_t)s*128))[l5];
            acc.x = fmaf(w, (float)u[0], acc.x);
            acc.y = fmaf(w, (float)u[1], acc.y);
            acc.z = fmaf(w, (float)u[2], acc.z);
            acc.w = fmaf(w, (float)u[3], acc.w);
        }
        __syncthreads();
    }

    if (t == 0) dsum1 = dtot;
    ((float4*)&part[wv*2 + half][0])[l5] = acc;
    __syncthreads();

    if (t < 128){
        float sgm = 0.f;
        #pragma unroll
        for (int p = 0; p < 8; p++) sgm += part[p][t];
        float val = sgm / (dsum1 + 1e-16f) + bias[t];
        out[(size_t)d*128 + t] = eluf(val);
    }
}

// ---------------------------------------------------------------------------
// out[i,j] = s1[i] + bedge + s2[j]. One block per row, nontemporal stores.
// ---------------------------------------------------------------------------
__global__ __launch_bounds__(256) void k_outer(
    const float* __restrict__ s1, const float* __restrict__ s2,
    const float* __restrict__ bedge,
    float* __restrict__ out, int n)
{
    int i = blockIdx.x;
    float a = s1[i] + bedge[0];
    f32x4* orow = (f32x4*)(out + (size_t)i * n);
    const f32x4* s2v = (const f32x4*)s2;
    int nq = n >> 2;
    for (int j = threadIdx.x; j < nq; j += blockDim.x){
        f32x4 b = s2v[j];
        f32x4 r = b + a;
        __builtin_nontemporal_store(r, &orow[j]);
    }
    int rem0 = nq << 2;
    for (int j = rem0 + threadIdx.x; j < n; j += blockDim.x)
        out[(size_t)i * n + j] = a + s2[j];
}

// ---------------------------------------------------------------------------
extern "C" void kernel_launch(void* const* d_in, const int* in_sizes, int n_in,
                              void* d_out, int out_size, void* d_ws, size_t ws_size,
                              hipStream_t stream) {
    const float* x     = (const float*)d_in[0];
    const int*   ei    = (const int*)  d_in[1];
    const float* W0    = (const float*)d_in[2];
    const float* as0w  = (const float*)d_in[3];
    const float* ad0w  = (const float*)d_in[4];
    const float* b0    = (const float*)d_in[5];
    const float* W1    = (const float*)d_in[6];
    const float* as1w  = (const float*)d_in[7];
    const float* ad1w  = (const float*)d_in[8];
    const float* b1    = (const float*)d_in[9];
    const float* Wout  = (const float*)d_in[10];
    const float* boutp = (const float*)d_in[11];
    const float* Wedge = (const float*)d_in[12];
    const float* bedge = (const float*)d_in[13];

    const int hid    = in_sizes[7];                 // 128
    const int heads  = in_sizes[3] / hid;           // 4
    const int in_dim = in_sizes[2] / (heads * hid); // 128
    const int n      = in_sizes[0] / in_dim;        // 10000
    const int E      = in_sizes[1] / 2;             // 320000
    const int NE     = E + n;
    const int F0     = heads * hid;                 // 512

    // ---- workspace carving ----
    // Zero-initialized region first (single memset): a0s a0d a1s a1d s1 s2 cnt
    char* ws = (char*)d_ws;
    size_t pos = 0;
    auto alloc = [&](size_t bytes) -> void* {
        pos = (pos + 255) & ~size_t(255);
        void* p = ws + pos;
        pos += bytes;
        return p;
    };
    float* a0s = (float*)alloc((size_t)n * heads * 4);
    float* a0d = (float*)alloc((size_t)n * heads * 4);
    float* a1s = (float*)alloc((size_t)n * 4);
    float* a1d = (float*)alloc((size_t)n * 4);
    float* s1  = (float*)alloc((size_t)n * 4);
    float* s2  = (float*)alloc((size_t)n * 4);
    int*   cnt = (int*)  alloc((size_t)n * 4);
    size_t zero_end = pos;                   // memset [ws, ws+zero_end)
    int*   offs= (int*)  alloc((size_t)(n + 1) * 4);
    int*   cur = (int*)  alloc((size_t)n * 4);

    // big buffers: in ws if they fit, else carve from d_out (dead before k_outer)
    auto al = [](size_t b){ return (b + 255) & ~size_t(255); };
    size_t b_esrc = al((size_t)NE * 4);
    size_t b_h0h  = al((size_t)n * F0 * 2);      // fp16
    size_t b_o1   = al((size_t)n * F0 * 4);      // fp32
    size_t b_h1h  = al((size_t)n * hid * 2);     // fp16
    size_t b_o2   = al((size_t)n * hid * 4);     // fp32
    size_t big_need = b_esrc + b_h0h + b_o1 + b_h1h + b_o2;
    size_t small_end = (pos + 255) & ~size_t(255);
    char* big = (small_end + big_need <= ws_size) ? (ws + small_end) : (char*)d_out;
    size_t bp = 0;
    int*   esrc = (int*)  (big + bp); bp += b_esrc;
    h16*   h0h  = (h16*)  (big + bp); bp += b_h0h;
    float* o1   = (float*)(big + bp); bp += b_o1;
    h16*   h1h  = (h16*)  (big + bp); bp += b_h1h;
    float* o2   = (float*)(big + bp); bp += b_o2;

    // ---- zero-init (atomic-epilogue targets + histogram) ----
    (void)hipMemsetAsync(ws, 0, zero_end, stream);

    // ---- CSR build (shared by both GAT layers) ----
    int tb = 256, gbE = (NE + tb - 1) / tb;
    k_hist   <<<gbE, tb, 0, stream>>>(ei, E, n, cnt);
    k_scan   <<<1, 1024, 0, stream>>>(cnt, n, offs, cur);
    k_scatter<<<gbE, tb, 0, stream>>>(ei, E, n, cur, esrc);

    int gx = (n + 63) / 64;

    // ---- Layer 1: h0h = fp16(x @ W0^T), a0s/a0d fused ; aggregate -> o1 ----
    k_gemm_h16_att<4><<<dim3(gx, F0/64), 256, 0, stream>>>(
        x, W0, h0h, as0w, ad0w, a0s, a0d, n, F0, in_dim);
    k_agg4<<<n, 256, 0, stream>>>(h0h, a0s, a0d, offs, esrc, b0, o1, n);

    // ---- Layer 2: h1h = fp16(o1 @ W1^T), a1s/a1d fused ; aggregate -> o2 ----
    k_gemm_h16_att<1><<<dim3(gx, hid/64), 256, 0, stream>>>(
        o1, W1, h1h, as1w, ad1w, a1s, a1d, n, hid, F0);
    k_agg1<<<n, 256, 0, stream>>>(h1h, a1s, a1d, offs, esrc, b1, o2, n);

    // ---- h3 = o2 @ Wout^T + bout fused directly into edge scores ----
    k_gemm_score<<<dim3(gx, hid/64), 256, 0, stream>>>(
        o2, Wout, boutp, Wedge, Wedge + hid, s1, s2, n, hid, hid);

    // ---- outer sum ----
    k_outer<<<n, 256, 0, stream>>>(s1, s2, bedge, (float*)d_out, n);
}